// Round 1
// baseline (106.162 us; speedup 1.0000x reference)
//
#include <hip/hip_runtime.h>
#include <math.h>

// RoPE_35424890257840: fused 3D-rotation + pair-RoPE on K and Q.
// N=131072 tokens, D=256, S=64, F=18 freqs, P=7*18=126 pairs.
// Layout: 16 threads per token; lane u owns elements 4u..4u+3 of each of the
// four 64-element segments (x,y,z,r). Both the (e,e+64,e+128) triple rotation
// and the (2p,2p+1) pair rotation are then thread-local -> zero shuffles.

namespace {

constexpr int kNTok = 131072;
constexpr int kD = 256;

__device__ __forceinline__ void pair_rot(int p, const float* lrow,
                                         const float* __restrict__ freqs,
                                         float& ka, float& kb,
                                         float& qa, float& qb) {
    const int j = p / 18;
    const int f = p - j * 18;
    const float ang = lrow[j] * freqs[f];
    float s, c;
    sincosf(ang, &s, &c);
    // K: Ka2 = c*Ka + s*Kb;  Kb2 = c*Kb - s*Ka2   (uses updated Ka2!)
    float ka2 = fmaf(s, kb, c * ka);
    kb = fmaf(-s, ka2, c * kb);
    ka = ka2;
    // Q: Qa2 = c*Qa - s*Qb;  Qb2 = c*Qb + s*Qa2
    float qa2 = fmaf(-s, qb, c * qa);
    qb = fmaf(s, qa2, c * qb);
    qa = qa2;
}

}  // namespace

__global__ __launch_bounds__(256) void rope_kernel(
    const float* __restrict__ Kin, const float* __restrict__ Qin,
    const float* __restrict__ loc, const float* __restrict__ freqs,
    float* __restrict__ Kout, float* __restrict__ Qout)
{
    const int gtid = blockIdx.x * blockDim.x + threadIdx.x;
    const int n = gtid >> 4;   // token
    const int u = gtid & 15;   // lane-within-token
    if (n >= kNTok) return;

    const size_t row = (size_t)n * kD;
    const float4* K4 = (const float4*)(Kin + row);
    const float4* Q4 = (const float4*)(Qin + row);
    float4 kx = K4[u], ky = K4[16 + u], kz = K4[32 + u], kr = K4[48 + u];
    float4 qx = Q4[u], qy = Q4[16 + u], qz = Q4[32 + u], qr = Q4[48 + u];

    const float* lrow = loc + (size_t)n * 7;
    float s4, c4, s5, c5, s6, c6;
    sincosf(lrow[4], &s4, &c4);
    sincosf(lrow[5], &s5, &c5);
    sincosf(lrow[6], &s6, &c6);

    // Stage 1: 3D rotation, componentwise over the float4.
    // K: (ky,kz)=rot(a6); (kx,kz)=rot(a5); (kx,ky)=rot(a4)   rot(A,B,a)=(cA+sB, cB-sA)
    // Q: (qx,qy)=rot(-a4); (qx,qz)=rot(-a5); (qy,qz)=rot(-a6)
#define ROT3(i)                                      \
    {                                                \
        float x = kx.i, y = ky.i, z = kz.i;          \
        float y1 = fmaf(s6, z, c6 * y);              \
        float z1 = fmaf(-s6, y, c6 * z);             \
        float x1 = fmaf(s5, z1, c5 * x);             \
        float z2 = fmaf(-s5, x, c5 * z1);            \
        kx.i = fmaf(s4, y1, c4 * x1);                \
        ky.i = fmaf(-s4, x1, c4 * y1);               \
        kz.i = z2;                                   \
        x = qx.i; y = qy.i; z = qz.i;                \
        float xq1 = fmaf(-s4, y, c4 * x);            \
        float yq1 = fmaf(s4, x, c4 * y);             \
        float xq2 = fmaf(-s5, z, c5 * xq1);          \
        float zq1 = fmaf(s5, xq1, c5 * z);           \
        qx.i = xq2;                                  \
        qy.i = fmaf(-s6, zq1, c6 * yq1);             \
        qz.i = fmaf(s6, yq1, c6 * zq1);              \
    }
    ROT3(x) ROT3(y) ROT3(z) ROT3(w)
#undef ROT3

    // Stage 2: pair rotation. Segment bases in pair-index space: x:0 y:32 z:64 r:96.
    const int p0 = 2 * u;
    pair_rot(p0,          lrow, freqs, kx.x, kx.y, qx.x, qx.y);
    pair_rot(p0 + 1,      lrow, freqs, kx.z, kx.w, qx.z, qx.w);
    pair_rot(32 + p0,     lrow, freqs, ky.x, ky.y, qy.x, qy.y);
    pair_rot(32 + p0 + 1, lrow, freqs, ky.z, ky.w, qy.z, qy.w);
    pair_rot(64 + p0,     lrow, freqs, kz.x, kz.y, qz.x, qz.y);
    pair_rot(64 + p0 + 1, lrow, freqs, kz.z, kz.w, qz.z, qz.w);
    if (u < 15) {  // pairs 96+2u, 97+2u valid only while < 126 (elements 252..255 pass through)
        pair_rot(96 + p0,     lrow, freqs, kr.x, kr.y, qr.x, qr.y);
        pair_rot(96 + p0 + 1, lrow, freqs, kr.z, kr.w, qr.z, qr.w);
    }

    float4* Ko = (float4*)(Kout + row);
    float4* Qo = (float4*)(Qout + row);
    Ko[u] = kx; Ko[16 + u] = ky; Ko[32 + u] = kz; Ko[48 + u] = kr;
    Qo[u] = qx; Qo[16 + u] = qy; Qo[32 + u] = qz; Qo[48 + u] = qr;
}

extern "C" void kernel_launch(void* const* d_in, const int* in_sizes, int n_in,
                              void* d_out, int out_size, void* d_ws, size_t ws_size,
                              hipStream_t stream) {
    const float* K     = (const float*)d_in[0];  // keyEmbeddings
    const float* Q     = (const float*)d_in[1];  // queryEmbeddings
    const float* loc   = (const float*)d_in[2];  // locations
    const float* freqs = (const float*)d_in[3];  // freqs
    float* Kout = (float*)d_out;                       // output 0: K
    float* Qout = Kout + (size_t)kNTok * kD;           // output 1: Q

    const int threads = 256;
    const int total_threads = kNTok * 16;              // 16 lanes per token
    const int blocks = (total_threads + threads - 1) / threads;  // 8192
    hipLaunchKernelGGL(rope_kernel, dim3(blocks), dim3(threads), 0, stream,
                       K, Q, loc, freqs, Kout, Qout);
}

// Round 3
// 101.737 us; speedup vs baseline: 1.0435x; 1.0435x over previous
//
#include <hip/hip_runtime.h>
#include <math.h>

// RoPE_35424890257840: fused 3D-rotation + pair-RoPE on K and Q.
// N=131072 tokens, D=256, S=64, F=18 freqs, P=7*18=126 pairs.
// Layout: 16 threads per token; lane u owns elements 4u..4u+3 of each of the
// four 64-element segments (x,y,z,r). Both the (e,e+64,e+128) triple rotation
// and the (2p,2p+1) pair rotation are then thread-local -> zero shuffles.
// R2 (resubmit after infra failure): libm sincosf -> __sincosf (hw
// v_sin/v_cos). Angles are small (loc~N(0,1) * freqs<=1), hw trig error
// ~1e-6 << 0.124 threshold.

namespace {

constexpr int kNTok = 131072;
constexpr int kD = 256;

__device__ __forceinline__ void pair_rot(int p, const float* lrow,
                                         const float* __restrict__ freqs,
                                         float& ka, float& kb,
                                         float& qa, float& qb) {
    const int j = p / 18;
    const int f = p - j * 18;
    const float ang = lrow[j] * freqs[f];
    float s, c;
    __sincosf(ang, &s, &c);
    // K: Ka2 = c*Ka + s*Kb;  Kb2 = c*Kb - s*Ka2   (uses updated Ka2!)
    float ka2 = fmaf(s, kb, c * ka);
    kb = fmaf(-s, ka2, c * kb);
    ka = ka2;
    // Q: Qa2 = c*Qa - s*Qb;  Qb2 = c*Qb + s*Qa2
    float qa2 = fmaf(-s, qb, c * qa);
    qb = fmaf(s, qa2, c * qb);
    qa = qa2;
}

}  // namespace

__global__ __launch_bounds__(256) void rope_kernel(
    const float* __restrict__ Kin, const float* __restrict__ Qin,
    const float* __restrict__ loc, const float* __restrict__ freqs,
    float* __restrict__ Kout, float* __restrict__ Qout)
{
    const int gtid = blockIdx.x * blockDim.x + threadIdx.x;
    const int n = gtid >> 4;   // token
    const int u = gtid & 15;   // lane-within-token
    if (n >= kNTok) return;

    const size_t row = (size_t)n * kD;
    const float4* K4 = (const float4*)(Kin + row);
    const float4* Q4 = (const float4*)(Qin + row);
    float4 kx = K4[u], ky = K4[16 + u], kz = K4[32 + u], kr = K4[48 + u];
    float4 qx = Q4[u], qy = Q4[16 + u], qz = Q4[32 + u], qr = Q4[48 + u];

    const float* lrow = loc + (size_t)n * 7;
    float s4, c4, s5, c5, s6, c6;
    __sincosf(lrow[4], &s4, &c4);
    __sincosf(lrow[5], &s5, &c5);
    __sincosf(lrow[6], &s6, &c6);

    // Stage 1: 3D rotation, componentwise over the float4.
    // K: (ky,kz)=rot(a6); (kx,kz)=rot(a5); (kx,ky)=rot(a4)   rot(A,B,a)=(cA+sB, cB-sA)
    // Q: (qx,qy)=rot(-a4); (qx,qz)=rot(-a5); (qy,qz)=rot(-a6)
#define ROT3(i)                                      \
    {                                                \
        float x = kx.i, y = ky.i, z = kz.i;          \
        float y1 = fmaf(s6, z, c6 * y);              \
        float z1 = fmaf(-s6, y, c6 * z);             \
        float x1 = fmaf(s5, z1, c5 * x);             \
        float z2 = fmaf(-s5, x, c5 * z1);            \
        kx.i = fmaf(s4, y1, c4 * x1);                \
        ky.i = fmaf(-s4, x1, c4 * y1);               \
        kz.i = z2;                                   \
        x = qx.i; y = qy.i; z = qz.i;                \
        float xq1 = fmaf(-s4, y, c4 * x);            \
        float yq1 = fmaf(s4, x, c4 * y);             \
        float xq2 = fmaf(-s5, z, c5 * xq1);          \
        float zq1 = fmaf(s5, xq1, c5 * z);           \
        qx.i = xq2;                                  \
        qy.i = fmaf(-s6, zq1, c6 * yq1);             \
        qz.i = fmaf(s6, yq1, c6 * zq1);              \
    }
    ROT3(x) ROT3(y) ROT3(z) ROT3(w)
#undef ROT3

    // Stage 2: pair rotation. Segment bases in pair-index space: x:0 y:32 z:64 r:96.
    const int p0 = 2 * u;
    pair_rot(p0,          lrow, freqs, kx.x, kx.y, qx.x, qx.y);
    pair_rot(p0 + 1,      lrow, freqs, kx.z, kx.w, qx.z, qx.w);
    pair_rot(32 + p0,     lrow, freqs, ky.x, ky.y, qy.x, qy.y);
    pair_rot(32 + p0 + 1, lrow, freqs, ky.z, ky.w, qy.z, qy.w);
    pair_rot(64 + p0,     lrow, freqs, kz.x, kz.y, qz.x, qz.y);
    pair_rot(64 + p0 + 1, lrow, freqs, kz.z, kz.w, qz.z, qz.w);
    if (u < 15) {  // pairs 96+2u, 97+2u valid only while < 126 (elements 252..255 pass through)
        pair_rot(96 + p0,     lrow, freqs, kr.x, kr.y, qr.x, qr.y);
        pair_rot(96 + p0 + 1, lrow, freqs, kr.z, kr.w, qr.z, qr.w);
    }

    float4* Ko = (float4*)(Kout + row);
    float4* Qo = (float4*)(Qout + row);
    Ko[u] = kx; Ko[16 + u] = ky; Ko[32 + u] = kz; Ko[48 + u] = kr;
    Qo[u] = qx; Qo[16 + u] = qy; Qo[32 + u] = qz; Qo[48 + u] = qr;
}

extern "C" void kernel_launch(void* const* d_in, const int* in_sizes, int n_in,
                              void* d_out, int out_size, void* d_ws, size_t ws_size,
                              hipStream_t stream) {
    const float* K     = (const float*)d_in[0];  // keyEmbeddings
    const float* Q     = (const float*)d_in[1];  // queryEmbeddings
    const float* loc   = (const float*)d_in[2];  // locations
    const float* freqs = (const float*)d_in[3];  // freqs
    float* Kout = (float*)d_out;                       // output 0: K
    float* Qout = Kout + (size_t)kNTok * kD;           // output 1: Q

    const int threads = 256;
    const int total_threads = kNTok * 16;              // 16 lanes per token
    const int blocks = (total_threads + threads - 1) / threads;  // 8192
    hipLaunchKernelGGL(rope_kernel, dim3(blocks), dim3(threads), 0, stream,
                       K, Q, loc, freqs, Kout, Qout);
}

// Round 6
// 90.223 us; speedup vs baseline: 1.1767x; 1.1276x over previous
//
#include <hip/hip_runtime.h>
#include <math.h>

// RoPE_35424890257840: fused 3D-rotation + pair-RoPE on K and Q.
// N=131072 tokens, D=256, S=64, F=18 freqs, P=7*18=126 pairs.
// Layout: 16 threads per token-array; lane u owns elements 4u..4u+3 of each
// of the four 64-element segments (x,y,z,r). Triple rotation (e,e+64,e+128)
// and pair rotation (2p,2p+1) are both thread-local -> zero shuffles.
// R5: R3 resubmit. ext_vector f4 only at the NT load/store boundary;
// compute on plain float arrays (vector elements can't bind to float&).

namespace {

constexpr int kNTok = 131072;
constexpr int kD = 256;
constexpr int kHalfThreads = kNTok * 16;  // 2M threads per array

typedef float f4 __attribute__((ext_vector_type(4)));

__device__ __forceinline__ f4 ntload(const float* p) {
    return __builtin_nontemporal_load((const f4*)p);
}
__device__ __forceinline__ void ntstore(float* p, f4 v) {
    __builtin_nontemporal_store(v, (f4*)p);
}

template <bool IS_K>
__device__ __forceinline__ void pair_rot(int p, const float* __restrict__ lrow,
                                         const float* __restrict__ freqs,
                                         float& a, float& b) {
    const int j = p / 18;
    const int f = p - j * 18;
    const float ang = lrow[j] * freqs[f];
    float s, c;
    __sincosf(ang, &s, &c);
    if constexpr (IS_K) {
        // Ka2 = c*Ka + s*Kb;  Kb2 = c*Kb - s*Ka2   (uses updated Ka2!)
        float a2 = fmaf(s, b, c * a);
        b = fmaf(-s, a2, c * b);
        a = a2;
    } else {
        // Qa2 = c*Qa - s*Qb;  Qb2 = c*Qb + s*Qa2
        float a2 = fmaf(-s, b, c * a);
        b = fmaf(s, a2, c * b);
        a = a2;
    }
}

template <bool IS_K>
__device__ __forceinline__ void process(const float* __restrict__ in,
                                        float* __restrict__ out,
                                        const float* __restrict__ loc,
                                        const float* __restrict__ freqs,
                                        int n, int u) {
    const size_t row = (size_t)n * kD;
    const float* A = in + row;
    f4 lx = ntload(A + 4 * u);
    f4 ly = ntload(A + 64 + 4 * u);
    f4 lz = ntload(A + 128 + 4 * u);
    f4 lr = ntload(A + 192 + 4 * u);
    float vx[4] = {lx.x, lx.y, lx.z, lx.w};
    float vy[4] = {ly.x, ly.y, ly.z, ly.w};
    float vz[4] = {lz.x, lz.y, lz.z, lz.w};
    float vr[4] = {lr.x, lr.y, lr.z, lr.w};

    const float* lrow = loc + (size_t)n * 7;
    float s4, c4, s5, c5, s6, c6;
    __sincosf(lrow[4], &s4, &c4);
    __sincosf(lrow[5], &s5, &c5);
    __sincosf(lrow[6], &s6, &c6);

    // Stage 1: 3D rotation, componentwise.  rot(A,B,a) = (cA+sB, cB-sA)
    // K: (ky,kz,a6); (kx,kz,a5); (kx,ky,a4)
    // Q: (qx,qy,-a4); (qx,qz,-a5); (qy,qz,-a6)
#pragma unroll
    for (int i = 0; i < 4; ++i) {
        float x = vx[i], y = vy[i], z = vz[i];
        if constexpr (IS_K) {
            float y1 = fmaf(s6, z, c6 * y);
            float z1 = fmaf(-s6, y, c6 * z);
            float x1 = fmaf(s5, z1, c5 * x);
            float z2 = fmaf(-s5, x, c5 * z1);
            vx[i] = fmaf(s4, y1, c4 * x1);
            vy[i] = fmaf(-s4, x1, c4 * y1);
            vz[i] = z2;
        } else {
            float x1 = fmaf(-s4, y, c4 * x);
            float y1 = fmaf(s4, x, c4 * y);
            float x2 = fmaf(-s5, z, c5 * x1);
            float z1 = fmaf(s5, x1, c5 * z);
            vx[i] = x2;
            vy[i] = fmaf(-s6, z1, c6 * y1);
            vz[i] = fmaf(s6, y1, c6 * z1);
        }
    }

    // Stage 2: pair rotation. Segment bases in pair-index space: x:0 y:32 z:64 r:96.
    const int p0 = 2 * u;
    pair_rot<IS_K>(p0,          lrow, freqs, vx[0], vx[1]);
    pair_rot<IS_K>(p0 + 1,      lrow, freqs, vx[2], vx[3]);
    pair_rot<IS_K>(32 + p0,     lrow, freqs, vy[0], vy[1]);
    pair_rot<IS_K>(32 + p0 + 1, lrow, freqs, vy[2], vy[3]);
    pair_rot<IS_K>(64 + p0,     lrow, freqs, vz[0], vz[1]);
    pair_rot<IS_K>(64 + p0 + 1, lrow, freqs, vz[2], vz[3]);
    if (u < 15) {  // pairs 96+2u,97+2u valid only while < 126 (elems 252..255 pass through)
        pair_rot<IS_K>(96 + p0,     lrow, freqs, vr[0], vr[1]);
        pair_rot<IS_K>(96 + p0 + 1, lrow, freqs, vr[2], vr[3]);
    }

    float* O = out + row;
    ntstore(O + 4 * u,       f4{vx[0], vx[1], vx[2], vx[3]});
    ntstore(O + 64 + 4 * u,  f4{vy[0], vy[1], vy[2], vy[3]});
    ntstore(O + 128 + 4 * u, f4{vz[0], vz[1], vz[2], vz[3]});
    ntstore(O + 192 + 4 * u, f4{vr[0], vr[1], vr[2], vr[3]});
}

}  // namespace

__global__ __launch_bounds__(256) void rope_kernel(
    const float* __restrict__ Kin, const float* __restrict__ Qin,
    const float* __restrict__ loc, const float* __restrict__ freqs,
    float* __restrict__ Kout, float* __restrict__ Qout)
{
    const int gtid = blockIdx.x * blockDim.x + threadIdx.x;
    // Blocks 0..8191 process K, 8192..16383 process Q: block-uniform split,
    // no lane divergence, half the live registers per path.
    if (gtid < kHalfThreads) {
        const int n = gtid >> 4;
        const int u = gtid & 15;
        process<true>(Kin, Kout, loc, freqs, n, u);
    } else {
        const int t = gtid - kHalfThreads;
        const int n = t >> 4;
        const int u = t & 15;
        process<false>(Qin, Qout, loc, freqs, n, u);
    }
}

extern "C" void kernel_launch(void* const* d_in, const int* in_sizes, int n_in,
                              void* d_out, int out_size, void* d_ws, size_t ws_size,
                              hipStream_t stream) {
    const float* K     = (const float*)d_in[0];  // keyEmbeddings
    const float* Q     = (const float*)d_in[1];  // queryEmbeddings
    const float* loc   = (const float*)d_in[2];  // locations
    const float* freqs = (const float*)d_in[3];  // freqs
    float* Kout = (float*)d_out;                       // output 0: K
    float* Qout = Kout + (size_t)kNTok * kD;           // output 1: Q

    const int threads = 256;
    const int blocks = (2 * kHalfThreads) / threads;   // 16384
    hipLaunchKernelGGL(rope_kernel, dim3(blocks), dim3(threads), 0, stream,
                       K, Q, loc, freqs, Kout, Qout);
}

// Round 8
// 90.169 us; speedup vs baseline: 1.1774x; 1.0006x over previous
//
#include <hip/hip_runtime.h>
#include <math.h>

// RoPE_35424890257840: fused 3D-rotation + pair-RoPE on K and Q.
// N=131072 tokens, D=256, S=64, F=18 freqs, P=7*18=126 pairs.
// Layout: 16 threads per token-array; lane u owns elements 4u..4u+3 of each
// of the four 64-element segments (x,y,z,r). Triple rotation (e,e+64,e+128)
// and pair rotation (2p,2p+1) are both thread-local -> zero shuffles.
// R7: resubmit of R6 after infra failure. __launch_bounds__(256, 8) ->
// cap 64 VGPR, 8 waves/SIMD, closing the 9% gap to the 6.29 TB/s ceiling
// (90.2 us @ 5.71 TB/s currently).

namespace {

constexpr int kNTok = 131072;
constexpr int kD = 256;
constexpr int kHalfThreads = kNTok * 16;  // 2M threads per array

typedef float f4 __attribute__((ext_vector_type(4)));

__device__ __forceinline__ f4 ntload(const float* p) {
    return __builtin_nontemporal_load((const f4*)p);
}
__device__ __forceinline__ void ntstore(float* p, f4 v) {
    __builtin_nontemporal_store(v, (f4*)p);
}

template <bool IS_K>
__device__ __forceinline__ void pair_rot(int p, const float* __restrict__ lrow,
                                         const float* __restrict__ freqs,
                                         float& a, float& b) {
    const int j = p / 18;
    const int f = p - j * 18;
    const float ang = lrow[j] * freqs[f];
    float s, c;
    __sincosf(ang, &s, &c);
    if constexpr (IS_K) {
        // Ka2 = c*Ka + s*Kb;  Kb2 = c*Kb - s*Ka2   (uses updated Ka2!)
        float a2 = fmaf(s, b, c * a);
        b = fmaf(-s, a2, c * b);
        a = a2;
    } else {
        // Qa2 = c*Qa - s*Qb;  Qb2 = c*Qb + s*Qa2
        float a2 = fmaf(-s, b, c * a);
        b = fmaf(s, a2, c * b);
        a = a2;
    }
}

template <bool IS_K>
__device__ __forceinline__ void process(const float* __restrict__ in,
                                        float* __restrict__ out,
                                        const float* __restrict__ loc,
                                        const float* __restrict__ freqs,
                                        int n, int u) {
    const size_t row = (size_t)n * kD;
    const float* A = in + row;
    f4 lx = ntload(A + 4 * u);
    f4 ly = ntload(A + 64 + 4 * u);
    f4 lz = ntload(A + 128 + 4 * u);
    f4 lr = ntload(A + 192 + 4 * u);
    float vx[4] = {lx.x, lx.y, lx.z, lx.w};
    float vy[4] = {ly.x, ly.y, ly.z, ly.w};
    float vz[4] = {lz.x, lz.y, lz.z, lz.w};
    float vr[4] = {lr.x, lr.y, lr.z, lr.w};

    const float* lrow = loc + (size_t)n * 7;
    float s4, c4, s5, c5, s6, c6;
    __sincosf(lrow[4], &s4, &c4);
    __sincosf(lrow[5], &s5, &c5);
    __sincosf(lrow[6], &s6, &c6);

    // Stage 1: 3D rotation, componentwise.  rot(A,B,a) = (cA+sB, cB-sA)
    // K: (ky,kz,a6); (kx,kz,a5); (kx,ky,a4)
    // Q: (qx,qy,-a4); (qx,qz,-a5); (qy,qz,-a6)
#pragma unroll
    for (int i = 0; i < 4; ++i) {
        float x = vx[i], y = vy[i], z = vz[i];
        if constexpr (IS_K) {
            float y1 = fmaf(s6, z, c6 * y);
            float z1 = fmaf(-s6, y, c6 * z);
            float x1 = fmaf(s5, z1, c5 * x);
            float z2 = fmaf(-s5, x, c5 * z1);
            vx[i] = fmaf(s4, y1, c4 * x1);
            vy[i] = fmaf(-s4, x1, c4 * y1);
            vz[i] = z2;
        } else {
            float x1 = fmaf(-s4, y, c4 * x);
            float y1 = fmaf(s4, x, c4 * y);
            float x2 = fmaf(-s5, z, c5 * x1);
            float z1 = fmaf(s5, x1, c5 * z);
            vx[i] = x2;
            vy[i] = fmaf(-s6, z1, c6 * y1);
            vz[i] = fmaf(s6, y1, c6 * z1);
        }
    }

    // Stage 2: pair rotation. Segment bases in pair-index space: x:0 y:32 z:64 r:96.
    const int p0 = 2 * u;
    pair_rot<IS_K>(p0,          lrow, freqs, vx[0], vx[1]);
    pair_rot<IS_K>(p0 + 1,      lrow, freqs, vx[2], vx[3]);
    pair_rot<IS_K>(32 + p0,     lrow, freqs, vy[0], vy[1]);
    pair_rot<IS_K>(32 + p0 + 1, lrow, freqs, vy[2], vy[3]);
    pair_rot<IS_K>(64 + p0,     lrow, freqs, vz[0], vz[1]);
    pair_rot<IS_K>(64 + p0 + 1, lrow, freqs, vz[2], vz[3]);
    if (u < 15) {  // pairs 96+2u,97+2u valid only while < 126 (elems 252..255 pass through)
        pair_rot<IS_K>(96 + p0,     lrow, freqs, vr[0], vr[1]);
        pair_rot<IS_K>(96 + p0 + 1, lrow, freqs, vr[2], vr[3]);
    }

    float* O = out + row;
    ntstore(O + 4 * u,       f4{vx[0], vx[1], vx[2], vx[3]});
    ntstore(O + 64 + 4 * u,  f4{vy[0], vy[1], vy[2], vy[3]});
    ntstore(O + 128 + 4 * u, f4{vz[0], vz[1], vz[2], vz[3]});
    ntstore(O + 192 + 4 * u, f4{vr[0], vr[1], vr[2], vr[3]});
}

}  // namespace

__global__ __launch_bounds__(256, 8) void rope_kernel(
    const float* __restrict__ Kin, const float* __restrict__ Qin,
    const float* __restrict__ loc, const float* __restrict__ freqs,
    float* __restrict__ Kout, float* __restrict__ Qout)
{
    const int gtid = blockIdx.x * blockDim.x + threadIdx.x;
    // Blocks 0..8191 process K, 8192..16383 process Q: block-uniform split,
    // no lane divergence, half the live registers per path.
    if (gtid < kHalfThreads) {
        const int n = gtid >> 4;
        const int u = gtid & 15;
        process<true>(Kin, Kout, loc, freqs, n, u);
    } else {
        const int t = gtid - kHalfThreads;
        const int n = t >> 4;
        const int u = t & 15;
        process<false>(Qin, Qout, loc, freqs, n, u);
    }
}

extern "C" void kernel_launch(void* const* d_in, const int* in_sizes, int n_in,
                              void* d_out, int out_size, void* d_ws, size_t ws_size,
                              hipStream_t stream) {
    const float* K     = (const float*)d_in[0];  // keyEmbeddings
    const float* Q     = (const float*)d_in[1];  // queryEmbeddings
    const float* loc   = (const float*)d_in[2];  // locations
    const float* freqs = (const float*)d_in[3];  // freqs
    float* Kout = (float*)d_out;                       // output 0: K
    float* Qout = Kout + (size_t)kNTok * kD;           // output 1: Q

    const int threads = 256;
    const int blocks = (2 * kHalfThreads) / threads;   // 16384
    hipLaunchKernelGGL(rope_kernel, dim3(blocks), dim3(threads), 0, stream,
                       K, Q, loc, freqs, Kout, Qout);
}